// Round 1
// baseline (344.018 us; speedup 1.0000x reference)
//
#include <hip/hip_runtime.h>

typedef unsigned short u16;
typedef __attribute__((ext_vector_type(8))) __bf16 bf16x8;
typedef __attribute__((ext_vector_type(8))) unsigned short u16x8;
typedef __attribute__((ext_vector_type(4))) float f32x4;

__device__ __forceinline__ float bf2f(u16 h) {
    return __uint_as_float(((unsigned int)h) << 16);
}
__device__ __forceinline__ u16 f2bf(float f) {
    unsigned int u = __float_as_uint(f);
    u += 0x7fffu + ((u >> 16) & 1u);   // round-to-nearest-even
    return (u16)(u >> 16);
}
__device__ __forceinline__ bf16x8 zero_bf16x8() {
    union { unsigned int u[4]; bf16x8 v; } z;
    z.u[0] = z.u[1] = z.u[2] = z.u[3] = 0u;
    return z.v;
}
__device__ __forceinline__ void gload_lds16(const void* g, void* l) {
    __builtin_amdgcn_global_load_lds(
        (const __attribute__((address_space(1))) unsigned int*)g,
        (__attribute__((address_space(3))) unsigned int*)l, 16, 0, 0);
}
__device__ __forceinline__ void store_out(u16* p, float v)  { *p = f2bf(v); }
__device__ __forceinline__ void store_out(float* p, float v){ *p = v; }

// ---------------- pre-pass kernels ----------------

__global__ __launch_bounds__(256) void cvt_f32_bf16(
    const float* __restrict__ in, u16* __restrict__ out, int n)
{
    int i = (blockIdx.x * 256 + threadIdx.x) * 8;
    if (i >= n) return;
    float4 a = *(const float4*)(in + i);
    float4 b = *(const float4*)(in + i + 4);
    u16x8 o;
    o[0] = f2bf(a.x); o[1] = f2bf(a.y); o[2] = f2bf(a.z); o[3] = f2bf(a.w);
    o[4] = f2bf(b.x); o[5] = f2bf(b.y); o[6] = f2bf(b.z); o[7] = f2bf(b.w);
    *(u16x8*)(out + i) = o;
}

// in: [K][F] f32 row-major -> out: [F][K] bf16 row-major
__global__ __launch_bounds__(256) void transpose_cvt(
    const float* __restrict__ in, u16* __restrict__ out, int K, int F)
{
    __shared__ u16 t[32][33];
    int f0 = blockIdx.x * 32;
    int k0 = blockIdx.y * 32;
    int lx = threadIdx.x & 31;
    int ly = threadIdx.x >> 5;   // 0..7
#pragma unroll
    for (int i = 0; i < 4; ++i) {
        int k = ly + i * 8;
        t[k][lx] = f2bf(in[(size_t)(k0 + k) * F + f0 + lx]);
    }
    __syncthreads();
#pragma unroll
    for (int i = 0; i < 4; ++i) {
        int fy = ly + i * 8;
        out[(size_t)(f0 + fy) * K + k0 + lx] = t[lx][fy];
    }
}

// d: [K][8][8] f32 (d[k][r][t]) -> dS: [T][K][8] bf16 (dS[t][k][r])
__global__ __launch_bounds__(256) void prep_d(
    const float* __restrict__ d, u16* __restrict__ o, int K)
{
    int i = blockIdx.x * 256 + threadIdx.x;
    if (i >= 8 * K * 8) return;
    int r = i & 7;
    int k = (i >> 3) % K;
    int t = i / (K * 8);
    o[i] = f2bf(d[((size_t)k * 8 + r) * 8 + t]);
}

// u: [8][F][8] f32 (u[r][f][t]) -> uS: [T][F][8] bf16, scaled by ALPHA/RANK = 2
__global__ __launch_bounds__(256) void prep_u(
    const float* __restrict__ u, u16* __restrict__ o, int F)
{
    int i = blockIdx.x * 256 + threadIdx.x;
    if (i >= 8 * F * 8) return;
    int r = i & 7;
    int f = (i >> 3) % F;
    int t = i / (F * 8);
    o[i] = f2bf(u[((size_t)r * F + f) * 8 + t] * 2.0f);
}

// ---------------- LoRA down-projection: A[row][r] = sum_k h[row][k]*dS[t][k][r]
__global__ __launch_bounds__(256) void lora_down(
    const u16* __restrict__ H, const u16* __restrict__ dS,
    u16* __restrict__ Aout, int K)
{
    int gt   = blockIdx.x * 256 + threadIdx.x;
    int row  = gt >> 3;
    int oct  = gt & 7;
    int task = row >> 10;     // 1024 rows per task
    const u16* hrow = H  + (size_t)row * K;
    const u16* dt   = dS + (size_t)task * K * 8;
    float acc[8];
#pragma unroll
    for (int r = 0; r < 8; ++r) acc[r] = 0.f;
    int kpt  = K >> 3;
    int kbeg = oct * kpt;
    for (int kk = kbeg; kk < kbeg + kpt; kk += 8) {
        u16x8 h8 = *(const u16x8*)(hrow + kk);
#pragma unroll
        for (int j = 0; j < 8; ++j) {
            float hv = bf2f(h8[j]);
            u16x8 dv = *(const u16x8*)(dt + (size_t)(kk + j) * 8);
#pragma unroll
            for (int r = 0; r < 8; ++r)
                acc[r] += hv * bf2f(dv[r]);
        }
    }
#pragma unroll
    for (int r = 0; r < 8; ++r) {
        acc[r] += __shfl_xor(acc[r], 1);
        acc[r] += __shfl_xor(acc[r], 2);
        acc[r] += __shfl_xor(acc[r], 4);
    }
    if (oct == 0) {
        u16x8 o;
#pragma unroll
        for (int r = 0; r < 8; ++r) o[r] = f2bf(acc[r]);
        *(u16x8*)(Aout + (size_t)row * 8) = o;
    }
}

// ---------------- fused GEMM + rank-8 LoRA epilogue + bias (+ReLU) ----------
// A: [M][K] bf16 row-major, BT: [N][K] bf16 (transposed weight),
// ALR: [M][8] bf16 (h@d_t), US: [T][N][8] bf16 (scaled u), bias: [N] f32.
#define BM 128
#define BN 128
#define BKT 64

template<int RELU, typename OUT_T>
__global__ __launch_bounds__(256) void gemm_lora(
    const u16* __restrict__ A, const u16* __restrict__ BT,
    const u16* __restrict__ ALR, const u16* __restrict__ US,
    const float* __restrict__ bias, OUT_T* __restrict__ C,
    int N, int K)
{
    __shared__ __align__(16) u16 sA[BM * BKT];
    __shared__ __align__(16) u16 sB[BN * BKT];

    const int tid  = threadIdx.x;
    const int lane = tid & 63;
    const int wave = tid >> 6;
    const int wr   = (wave >> 1) * 64;   // wave row offset in tile
    const int wc   = (wave & 1) * 64;    // wave col offset in tile
    const int l15  = lane & 15;
    const int lg   = lane >> 4;          // lane group 0..3

    const int nbn  = N >> 7;
    const int bm   = blockIdx.x / nbn;
    const int bn   = blockIdx.x % nbn;
    const int brow = bm << 7;
    const int bcol = bn << 7;
    const int task = brow >> 10;

    f32x4 acc[4][4];
    const f32x4 zf = {0.f, 0.f, 0.f, 0.f};
#pragma unroll
    for (int m = 0; m < 4; ++m)
#pragma unroll
        for (int n = 0; n < 4; ++n) acc[m][n] = zf;

    const u16* gA0 = A  + (size_t)brow * K;
    const u16* gB0 = BT + (size_t)bcol * K;

    for (int kt = 0; kt < K; kt += BKT) {
        // stage 128x64 A-tile and 128x64 B^T-tile, 16B per lane per issue
#pragma unroll
        for (int i = 0; i < 4; ++i) {
            int e = i * 2048 + tid * 8;     // element index in 8192-elem tile
            int r = e >> 6;                 // tile row
            int c = e & 63;                 // tile k
            gload_lds16(gA0 + (size_t)r * K + kt + c, &sA[e]);
            gload_lds16(gB0 + (size_t)r * K + kt + c, &sB[e]);
        }
        __syncthreads();
#pragma unroll
        for (int ks = 0; ks < 2; ++ks) {
            bf16x8 aF[4], bF[4];
#pragma unroll
            for (int m = 0; m < 4; ++m)
                aF[m] = *(const bf16x8*)&sA[(wr + m * 16 + l15) * BKT + ks * 32 + lg * 8];
#pragma unroll
            for (int n = 0; n < 4; ++n)
                bF[n] = *(const bf16x8*)&sB[(wc + n * 16 + l15) * BKT + ks * 32 + lg * 8];
#pragma unroll
            for (int m = 0; m < 4; ++m)
#pragma unroll
                for (int n = 0; n < 4; ++n)
                    acc[m][n] = __builtin_amdgcn_mfma_f32_16x16x32_bf16(
                        aF[m], bF[n], acc[m][n], 0, 0, 0);
        }
        __syncthreads();
    }

    // rank-8 LoRA delta: one extra MFMA round, k in [0,8) valid, rest zero
    bf16x8 z8 = zero_bf16x8();
    bf16x8 aL[4], bU[4];
#pragma unroll
    for (int m = 0; m < 4; ++m) {
        int row = brow + wr + m * 16 + l15;
        aL[m] = (lg == 0) ? *(const bf16x8*)(ALR + (size_t)row * 8) : z8;
    }
#pragma unroll
    for (int n = 0; n < 4; ++n) {
        int col = bcol + wc + n * 16 + l15;
        bU[n] = (lg == 0) ? *(const bf16x8*)(US + ((size_t)task * N + col) * 8) : z8;
    }
#pragma unroll
    for (int m = 0; m < 4; ++m)
#pragma unroll
        for (int n = 0; n < 4; ++n)
            acc[m][n] = __builtin_amdgcn_mfma_f32_16x16x32_bf16(
                aL[m], bU[n], acc[m][n], 0, 0, 0);

    // bias (+ReLU) + store; C/D layout: col = lane&15, row = (lane>>4)*4+reg
#pragma unroll
    for (int n = 0; n < 4; ++n) {
        int col  = bcol + wc + n * 16 + l15;
        float bv = bias[col];
#pragma unroll
        for (int m = 0; m < 4; ++m) {
            int row0 = brow + wr + m * 16 + lg * 4;
#pragma unroll
            for (int r = 0; r < 4; ++r) {
                float v = acc[m][n][r] + bv;
                if (RELU) v = fmaxf(v, 0.0f);
                store_out(&C[(size_t)(row0 + r) * N + col], v);
            }
        }
    }
}

// ---------------- launch ----------------

extern "C" void kernel_launch(void* const* d_in, const int* in_sizes, int n_in,
                              void* d_out, int out_size, void* d_ws, size_t ws_size,
                              hipStream_t stream) {
    const float* x  = (const float*)d_in[0];
    const float* k0 = (const float*)d_in[1];
    const float* b0 = (const float*)d_in[2];
    const float* d0 = (const float*)d_in[3];
    const float* u0 = (const float*)d_in[4];
    const float* k1 = (const float*)d_in[5];
    const float* b1 = (const float*)d_in[6];
    const float* d1 = (const float*)d_in[7];
    const float* u1 = (const float*)d_in[8];
    const float* k2 = (const float*)d_in[9];
    const float* b2 = (const float*)d_in[10];
    const float* d2 = (const float*)d_in[11];
    const float* u2 = (const float*)d_in[12];

    const int T = 8, B = 1024, D = 1024, H1 = 2048, H2 = 2048, H3 = 1024;
    const int M = T * B;

    u16* w = (u16*)d_ws;
    size_t off = 0;
    u16* xb  = w + off; off += (size_t)M * D;
    u16* k0T = w + off; off += (size_t)H1 * D;
    u16* k1T = w + off; off += (size_t)H2 * H1;
    u16* k2T = w + off; off += (size_t)H3 * H2;
    u16* dS0 = w + off; off += (size_t)T * D * 8;
    u16* dS1 = w + off; off += (size_t)T * H1 * 8;
    u16* dS2 = w + off; off += (size_t)T * H2 * 8;
    u16* uS0 = w + off; off += (size_t)T * H1 * 8;
    u16* uS1 = w + off; off += (size_t)T * H2 * 8;
    u16* uS2 = w + off; off += (size_t)T * H3 * 8;
    u16* h1  = w + off; off += (size_t)M * H1;
    u16* h2  = w + off; off += (size_t)M * H2;
    u16* Ab  = w + off; off += (size_t)M * 8;
    (void)ws_size; (void)in_sizes; (void)n_in; (void)out_size;

    // pre-pass: dtype conversion / transposes / repacks
    cvt_f32_bf16<<<(M * D) / 2048, 256, 0, stream>>>(x, xb, M * D);
    transpose_cvt<<<dim3(H1 / 32, D  / 32), 256, 0, stream>>>(k0, k0T, D,  H1);
    transpose_cvt<<<dim3(H2 / 32, H1 / 32), 256, 0, stream>>>(k1, k1T, H1, H2);
    transpose_cvt<<<dim3(H3 / 32, H2 / 32), 256, 0, stream>>>(k2, k2T, H2, H3);
    prep_d<<<(T * D  * 8) / 256, 256, 0, stream>>>(d0, dS0, D);
    prep_d<<<(T * H1 * 8) / 256, 256, 0, stream>>>(d1, dS1, H1);
    prep_d<<<(T * H2 * 8) / 256, 256, 0, stream>>>(d2, dS2, H2);
    prep_u<<<(T * H1 * 8) / 256, 256, 0, stream>>>(u0, uS0, H1);
    prep_u<<<(T * H2 * 8) / 256, 256, 0, stream>>>(u1, uS1, H2);
    prep_u<<<(T * H3 * 8) / 256, 256, 0, stream>>>(u2, uS2, H3);

    // layer 0: h1 = relu(x@k0 + b0 + (x@d0)@u0*2)
    lora_down<<<(M * 8) / 256, 256, 0, stream>>>(xb, dS0, Ab, D);
    gemm_lora<1, u16><<<(M / BM) * (H1 / BN), 256, 0, stream>>>(
        xb, k0T, Ab, uS0, b0, h1, H1, D);
    // layer 1
    lora_down<<<(M * 8) / 256, 256, 0, stream>>>(h1, dS1, Ab, H1);
    gemm_lora<1, u16><<<(M / BM) * (H2 / BN), 256, 0, stream>>>(
        h1, k1T, Ab, uS1, b1, h2, H2, H1);
    // layer 2 (no relu, fp32 out)
    lora_down<<<(M * 8) / 256, 256, 0, stream>>>(h2, dS2, Ab, H2);
    gemm_lora<0, float><<<(M / BM) * (H3 / BN), 256, 0, stream>>>(
        h2, k2T, Ab, uS2, b2, (float*)d_out, H3, H2);
}

// Round 2
// 326.665 us; speedup vs baseline: 1.0531x; 1.0531x over previous
//
#include <hip/hip_runtime.h>

typedef unsigned short u16;
typedef __attribute__((ext_vector_type(8))) __bf16 bf16x8;
typedef __attribute__((ext_vector_type(8))) unsigned short u16x8;
typedef __attribute__((ext_vector_type(4))) float f32x4;

__device__ __forceinline__ float bf2f(u16 h) {
    return __uint_as_float(((unsigned int)h) << 16);
}
__device__ __forceinline__ u16 f2bf(float f) {
    unsigned int u = __float_as_uint(f);
    u += 0x7fffu + ((u >> 16) & 1u);   // round-to-nearest-even
    return (u16)(u >> 16);
}
__device__ __forceinline__ bf16x8 zero_bf16x8() {
    union { unsigned int u[4]; bf16x8 v; } z;
    z.u[0] = z.u[1] = z.u[2] = z.u[3] = 0u;
    return z.v;
}
__device__ __forceinline__ void gload_lds16(const void* g, void* l) {
    __builtin_amdgcn_global_load_lds(
        (const __attribute__((address_space(1))) unsigned int*)g,
        (__attribute__((address_space(3))) unsigned int*)l, 16, 0, 0);
}
__device__ __forceinline__ void store_out(u16* p, float v)  { *p = f2bf(v); }
__device__ __forceinline__ void store_out(float* p, float v){ *p = v; }

// ---------------- pre-pass kernels (unchanged from R1) ----------------

__global__ __launch_bounds__(256) void cvt_f32_bf16(
    const float* __restrict__ in, u16* __restrict__ out, int n)
{
    int i = (blockIdx.x * 256 + threadIdx.x) * 8;
    if (i >= n) return;
    float4 a = *(const float4*)(in + i);
    float4 b = *(const float4*)(in + i + 4);
    u16x8 o;
    o[0] = f2bf(a.x); o[1] = f2bf(a.y); o[2] = f2bf(a.z); o[3] = f2bf(a.w);
    o[4] = f2bf(b.x); o[5] = f2bf(b.y); o[6] = f2bf(b.z); o[7] = f2bf(b.w);
    *(u16x8*)(out + i) = o;
}

__global__ __launch_bounds__(256) void transpose_cvt(
    const float* __restrict__ in, u16* __restrict__ out, int K, int F)
{
    __shared__ u16 t[32][33];
    int f0 = blockIdx.x * 32;
    int k0 = blockIdx.y * 32;
    int lx = threadIdx.x & 31;
    int ly = threadIdx.x >> 5;
#pragma unroll
    for (int i = 0; i < 4; ++i) {
        int k = ly + i * 8;
        t[k][lx] = f2bf(in[(size_t)(k0 + k) * F + f0 + lx]);
    }
    __syncthreads();
#pragma unroll
    for (int i = 0; i < 4; ++i) {
        int fy = ly + i * 8;
        out[(size_t)(f0 + fy) * K + k0 + lx] = t[lx][fy];
    }
}

__global__ __launch_bounds__(256) void prep_d(
    const float* __restrict__ d, u16* __restrict__ o, int K)
{
    int i = blockIdx.x * 256 + threadIdx.x;
    if (i >= 8 * K * 8) return;
    int r = i & 7;
    int k = (i >> 3) % K;
    int t = i / (K * 8);
    o[i] = f2bf(d[((size_t)k * 8 + r) * 8 + t]);
}

__global__ __launch_bounds__(256) void prep_u(
    const float* __restrict__ u, u16* __restrict__ o, int F)
{
    int i = blockIdx.x * 256 + threadIdx.x;
    if (i >= 8 * F * 8) return;
    int r = i & 7;
    int f = (i >> 3) % F;
    int t = i / (F * 8);
    o[i] = f2bf(u[((size_t)r * F + f) * 8 + t] * 2.0f);
}

// ---------------- LoRA down-projection (unchanged) ----------------
__global__ __launch_bounds__(256) void lora_down(
    const u16* __restrict__ H, const u16* __restrict__ dS,
    u16* __restrict__ Aout, int K)
{
    int gt   = blockIdx.x * 256 + threadIdx.x;
    int row  = gt >> 3;
    int oct  = gt & 7;
    int task = row >> 10;
    const u16* hrow = H  + (size_t)row * K;
    const u16* dt   = dS + (size_t)task * K * 8;
    float acc[8];
#pragma unroll
    for (int r = 0; r < 8; ++r) acc[r] = 0.f;
    int kpt  = K >> 3;
    int kbeg = oct * kpt;
    for (int kk = kbeg; kk < kbeg + kpt; kk += 8) {
        u16x8 h8 = *(const u16x8*)(hrow + kk);
#pragma unroll
        for (int j = 0; j < 8; ++j) {
            float hv = bf2f(h8[j]);
            u16x8 dv = *(const u16x8*)(dt + (size_t)(kk + j) * 8);
#pragma unroll
            for (int r = 0; r < 8; ++r)
                acc[r] += hv * bf2f(dv[r]);
        }
    }
#pragma unroll
    for (int r = 0; r < 8; ++r) {
        acc[r] += __shfl_xor(acc[r], 1);
        acc[r] += __shfl_xor(acc[r], 2);
        acc[r] += __shfl_xor(acc[r], 4);
    }
    if (oct == 0) {
        u16x8 o;
#pragma unroll
        for (int r = 0; r < 8; ++r) o[r] = f2bf(acc[r]);
        *(u16x8*)(Aout + (size_t)row * 8) = o;
    }
}

// ============ 256x256 8-phase GEMM + rank-8 LoRA epilogue (m201 port) ======
// A: [M][K] bf16, BT: [N][K] bf16, ALR: [M][8], US: [T][N][8], bias: [N] f32.
// 512 threads = 8 waves (2M x 4N). Per-wave out 128x64, frag-interleaved:
//   row(m) = m*32 + wr*16, m=0..7 ; col(n) = n*64 + wc*16, n=0..3.
// LDS: sA/sB [2 dbuf][256*64] bf16 = 128 KiB. st_16x32 swizzle byte^=((b>>9)&1)<<5.
// Phase p computes quadrant (mh,nh) in order (0,0)(0,1)(1,0)(1,1) per K-tile.
// Half usage: A-half(mh) read in phases {2mh,2mh+1}... actually A0:{P0,P1},
// A1:{P2,P3}, B0:{P0,P2}, B1:{P1,P3} (B via reg reuse: LDS reads B0@P0, B1@P1).
// Stage slots (1 half = 2 gload_lds per phase), steady state iteration i
// (tiles a=2i from buf0 @P0-3, b=2i+1 from buf1 @P4-7):
//   P0: buf1.A1<-t(2i+1)  [buf1.A1 last read prev-P7]
//   P1: buf1.B1<-t(2i+1)  [last read prev-P7 (reg-reuse; LDS read prev-P5)]
//   P2: buf0.A0<-t(2i+2)  [A0 last read P1]
//   P3: buf0.B0<-t(2i+2)  [B0 LDS-read only at P0]
//   P4: buf0.A1<-t(2i+2)  [A1 last read P3]
//   P5: buf0.B1<-t(2i+2)  [B1 LDS-read only at P1]
//   P6: buf1.A0<-t(2i+3)  [buf1.A0 last read P5]
//   P7: buf1.B0<-t(2i+3)  [buf1.B0 LDS-read only at P4]
// Waits: vmcnt(4) at end-P3 (ensures prev-P6,P7+P0,P1 done -> buf1 tile ready;
// P2,P3's 4 loads stay in flight) and end-P7 (ensures P2-P5 done -> buf0 tile
// ready; P6,P7 in flight). Last iteration: stages P2-P7 skipped, waits drain 0.

#define WAIT_VM4  asm volatile("s_waitcnt vmcnt(4)" ::: "memory")
#define WAIT_VM0  asm volatile("s_waitcnt vmcnt(0)" ::: "memory")
#define WAIT_LGKM0 do { asm volatile("s_waitcnt lgkmcnt(0)" ::: "memory"); \
                        __builtin_amdgcn_sched_barrier(0); } while (0)
#define BARRIER   asm volatile("s_barrier" ::: "memory")
#define PRIO1     __builtin_amdgcn_s_setprio(1)
#define PRIO0     __builtin_amdgcn_s_setprio(0)

#define DS_A(c, mh) do { \
    _Pragma("unroll") for (int mm = 0; mm < 4; ++mm) \
    _Pragma("unroll") for (int ks = 0; ks < 2; ++ks) \
        aF[mm][ks] = *(const bf16x8*)((const char*)&sA[c][0] + \
                       abase + ((mh)*4+mm)*4096 + ks*64); } while (0)

#define DS_B(c, nh, bset) do { \
    _Pragma("unroll") for (int nn = 0; nn < 2; ++nn) \
    _Pragma("unroll") for (int ks = 0; ks < 2; ++ks) \
        bset[nn][ks] = *(const bf16x8*)((const char*)&sB[c][0] + \
                       bbase + ((nh)*2+nn)*8192 + ks*64); } while (0)

#define MFMAQ(mh, nh, bset) do { \
    _Pragma("unroll") for (int mm = 0; mm < 4; ++mm) \
    _Pragma("unroll") for (int nn = 0; nn < 2; ++nn) \
    _Pragma("unroll") for (int ks = 0; ks < 2; ++ks) \
        acc[(mh)*4+mm][(nh)*2+nn] = __builtin_amdgcn_mfma_f32_16x16x32_bf16( \
            aF[mm][ks], bset[nn][ks], acc[(mh)*4+mm][(nh)*2+nn], 0, 0, 0); } while (0)

#define STAGE_A(c, h, kt) do { \
    _Pragma("unroll") for (int s = 0; s < 2; ++s) { \
        int P_ = (h)*16384 + s*8192 + tid*16; \
        gload_lds16((const char*)A + (size_t)(unsigned)(aoff[(h)*2+s] + (kt)*128), \
                    (char*)&sA[c][0] + P_); } } while (0)

#define STAGE_B(c, h, kt) do { \
    _Pragma("unroll") for (int s = 0; s < 2; ++s) { \
        int P_ = (h)*16384 + s*8192 + tid*16; \
        gload_lds16((const char*)BT + (size_t)(unsigned)(boff[(h)*2+s] + (kt)*128), \
                    (char*)&sB[c][0] + P_); } } while (0)

template<int RELU, typename OUT_T>
__global__ __launch_bounds__(512, 2) void gemm_lora8(
    const u16* __restrict__ A, const u16* __restrict__ BT,
    const u16* __restrict__ ALR, const u16* __restrict__ US,
    const float* __restrict__ bias, OUT_T* __restrict__ C,
    int N, int K)
{
    __shared__ __align__(16) u16 sA[2][256 * 64];
    __shared__ __align__(16) u16 sB[2][256 * 64];

    const int tid  = threadIdx.x;
    const int lane = tid & 63;
    const int wave = tid >> 6;
    const int wr   = wave >> 2;   // 0..1
    const int wc   = wave & 3;    // 0..3
    const int l15  = lane & 15;
    const int lg   = lane >> 4;

    // bijective XCD swizzle (m204)
    const int nwg = gridDim.x;
    const int orig = blockIdx.x;
    const int q = nwg >> 3, r = nwg & 7;
    const int x = orig & 7, o = orig >> 3;
    const int wg = (x < r ? x * (q + 1) : r * (q + 1) + (x - r) * q) + o;
    const int nbn  = N >> 8;
    const int bm   = wg / nbn;
    const int bn   = wg % nbn;
    const int brow = bm << 8;
    const int bcol = bn << 8;
    const int task = brow >> 10;

    // staging offsets: physical LDS slot P -> logical (row,colb) via swizzle,
    // global byte offset (excl. kt) per (half,s)
    int aoff[4], boff[4];
#pragma unroll
    for (int h = 0; h < 2; ++h)
#pragma unroll
        for (int s = 0; s < 2; ++s) {
            int P = h * 16384 + s * 8192 + tid * 16;
            int L = P ^ (((P >> 9) & 1) << 5);
            int row = L >> 7, colb = L & 127;
            aoff[h * 2 + s] = (brow + row) * K * 2 + colb;
            boff[h * 2 + s] = (bcol + row) * K * 2 + colb;
        }

    // ds_read bases (swizzle folds to a per-thread constant: lin bit9 = row bit2
    // = l15 bit2, independent of m/n/ks)
    const int xor5  = ((l15 >> 2) & 1) << 5;
    const int abase = (wr * 16 + l15) * 128 + ((lg * 16) ^ xor5);
    const int bbase = (wc * 16 + l15) * 128 + ((lg * 16) ^ xor5);

    f32x4 acc[8][4];
    const f32x4 zf = {0.f, 0.f, 0.f, 0.f};
#pragma unroll
    for (int m = 0; m < 8; ++m)
#pragma unroll
        for (int n = 0; n < 4; ++n) acc[m][n] = zf;

    bf16x8 aF[4][2], bF0[2][2], bF1[2][2];

    // prologue: buf0 <- tile0 (all 4 halves), buf1 <- tile1 A0,B0 (12 loads)
    STAGE_A(0, 0, 0); STAGE_B(0, 0, 0); STAGE_A(0, 1, 0); STAGE_B(0, 1, 0);
    STAGE_A(1, 0, 1); STAGE_B(1, 0, 1);
    WAIT_VM4;          // tile0's 8 loads complete; buf1 A0,B0 in flight
    BARRIER;

    const int iters = K >> 7;   // K/128: two BK=64 tiles per iteration
    for (int i = 0; i < iters; ++i) {
        const int t1 = 2 * i + 1, t2 = 2 * i + 2, t3 = 2 * i + 3;
        const bool nl = (i + 1 < iters);

        // P0: quad(0,0) buf0 ; stage buf1.A1 <- t1
        DS_A(0, 0); DS_B(0, 0, bF0);
        STAGE_A(1, 1, t1);
        BARRIER; WAIT_LGKM0;
        PRIO1; MFMAQ(0, 0, bF0); PRIO0;
        BARRIER;
        // P1: quad(0,1) buf0 ; stage buf1.B1 <- t1
        DS_B(0, 1, bF1);
        STAGE_B(1, 1, t1);
        BARRIER; WAIT_LGKM0;
        PRIO1; MFMAQ(0, 1, bF1); PRIO0;
        BARRIER;
        // P2: quad(1,0) buf0 (B0 reg-reuse) ; stage buf0.A0 <- t2
        DS_A(0, 1);
        if (nl) STAGE_A(0, 0, t2);
        BARRIER; WAIT_LGKM0;
        PRIO1; MFMAQ(1, 0, bF0); PRIO0;
        BARRIER;
        // P3: quad(1,1) buf0 (B1 reg-reuse) ; stage buf0.B0 <- t2 ; vmcnt
        if (nl) STAGE_B(0, 0, t2);
        BARRIER; WAIT_LGKM0;
        PRIO1; MFMAQ(1, 1, bF1); PRIO0;
        if (nl) { WAIT_VM4; } else { WAIT_VM0; }
        BARRIER;
        // P4: quad(0,0) buf1 ; stage buf0.A1 <- t2
        DS_A(1, 0); DS_B(1, 0, bF0);
        if (nl) STAGE_A(0, 1, t2);
        BARRIER; WAIT_LGKM0;
        PRIO1; MFMAQ(0, 0, bF0); PRIO0;
        BARRIER;
        // P5: quad(0,1) buf1 ; stage buf0.B1 <- t2
        DS_B(1, 1, bF1);
        if (nl) STAGE_B(0, 1, t2);
        BARRIER; WAIT_LGKM0;
        PRIO1; MFMAQ(0, 1, bF1); PRIO0;
        BARRIER;
        // P6: quad(1,0) buf1 ; stage buf1.A0 <- t3
        DS_A(1, 1);
        if (nl) STAGE_A(1, 0, t3);
        BARRIER; WAIT_LGKM0;
        PRIO1; MFMAQ(1, 0, bF0); PRIO0;
        BARRIER;
        // P7: quad(1,1) buf1 ; stage buf1.B0 <- t3 ; vmcnt
        if (nl) STAGE_B(1, 0, t3);
        BARRIER; WAIT_LGKM0;
        PRIO1; MFMAQ(1, 1, bF1); PRIO0;
        if (nl) { WAIT_VM4; } else { WAIT_VM0; }
        BARRIER;
    }

    // rank-8 LoRA delta: one extra MFMA round (k 0..7 valid, lanes lg>0 zero)
    bf16x8 z8 = zero_bf16x8();
    bf16x8 bU[4];
#pragma unroll
    for (int n = 0; n < 4; ++n) {
        int col = bcol + n * 64 + wc * 16 + l15;
        bU[n] = (lg == 0) ? *(const bf16x8*)(US + ((size_t)task * N + col) * 8) : z8;
    }
#pragma unroll
    for (int m = 0; m < 8; ++m) {
        int row = brow + m * 32 + wr * 16 + l15;
        bf16x8 aL = (lg == 0) ? *(const bf16x8*)(ALR + (size_t)row * 8) : z8;
#pragma unroll
        for (int n = 0; n < 4; ++n)
            acc[m][n] = __builtin_amdgcn_mfma_f32_16x16x32_bf16(
                aL, bU[n], acc[m][n], 0, 0, 0);
    }

    // bias (+ReLU) + store; C/D: col = lane&15, row = lg*4 + reg
#pragma unroll
    for (int n = 0; n < 4; ++n) {
        int col  = bcol + n * 64 + wc * 16 + l15;
        float bv = bias[col];
#pragma unroll
        for (int m = 0; m < 8; ++m) {
            int row0 = brow + m * 32 + wr * 16 + lg * 4;
#pragma unroll
            for (int rr = 0; rr < 4; ++rr) {
                float v = acc[m][n][rr] + bv;
                if (RELU) v = fmaxf(v, 0.0f);
                store_out(&C[(size_t)(row0 + rr) * N + col], v);
            }
        }
    }
}

// ---------------- launch ----------------

extern "C" void kernel_launch(void* const* d_in, const int* in_sizes, int n_in,
                              void* d_out, int out_size, void* d_ws, size_t ws_size,
                              hipStream_t stream) {
    const float* x  = (const float*)d_in[0];
    const float* k0 = (const float*)d_in[1];
    const float* b0 = (const float*)d_in[2];
    const float* d0 = (const float*)d_in[3];
    const float* u0 = (const float*)d_in[4];
    const float* k1 = (const float*)d_in[5];
    const float* b1 = (const float*)d_in[6];
    const float* d1 = (const float*)d_in[7];
    const float* u1 = (const float*)d_in[8];
    const float* k2 = (const float*)d_in[9];
    const float* b2 = (const float*)d_in[10];
    const float* d2 = (const float*)d_in[11];
    const float* u2 = (const float*)d_in[12];

    const int T = 8, B = 1024, D = 1024, H1 = 2048, H2 = 2048, H3 = 1024;
    const int M = T * B;

    u16* w = (u16*)d_ws;
    size_t off = 0;
    u16* xb  = w + off; off += (size_t)M * D;
    u16* k0T = w + off; off += (size_t)H1 * D;
    u16* k1T = w + off; off += (size_t)H2 * H1;
    u16* k2T = w + off; off += (size_t)H3 * H2;
    u16* dS0 = w + off; off += (size_t)T * D * 8;
    u16* dS1 = w + off; off += (size_t)T * H1 * 8;
    u16* dS2 = w + off; off += (size_t)T * H2 * 8;
    u16* uS0 = w + off; off += (size_t)T * H1 * 8;
    u16* uS1 = w + off; off += (size_t)T * H2 * 8;
    u16* uS2 = w + off; off += (size_t)T * H3 * 8;
    u16* h1  = w + off; off += (size_t)M * H1;
    u16* h2  = w + off; off += (size_t)M * H2;
    u16* Ab  = w + off; off += (size_t)M * 8;
    (void)ws_size; (void)in_sizes; (void)n_in; (void)out_size;

    cvt_f32_bf16<<<(M * D) / 2048, 256, 0, stream>>>(x, xb, M * D);
    transpose_cvt<<<dim3(H1 / 32, D  / 32), 256, 0, stream>>>(k0, k0T, D,  H1);
    transpose_cvt<<<dim3(H2 / 32, H1 / 32), 256, 0, stream>>>(k1, k1T, H1, H2);
    transpose_cvt<<<dim3(H3 / 32, H2 / 32), 256, 0, stream>>>(k2, k2T, H2, H3);
    prep_d<<<(T * D  * 8) / 256, 256, 0, stream>>>(d0, dS0, D);
    prep_d<<<(T * H1 * 8) / 256, 256, 0, stream>>>(d1, dS1, H1);
    prep_d<<<(T * H2 * 8) / 256, 256, 0, stream>>>(d2, dS2, H2);
    prep_u<<<(T * H1 * 8) / 256, 256, 0, stream>>>(u0, uS0, H1);
    prep_u<<<(T * H2 * 8) / 256, 256, 0, stream>>>(u1, uS1, H2);
    prep_u<<<(T * H3 * 8) / 256, 256, 0, stream>>>(u2, uS2, H3);

    // layer 0
    lora_down<<<(M * 8) / 256, 256, 0, stream>>>(xb, dS0, Ab, D);
    gemm_lora8<1, u16><<<(M / 256) * (H1 / 256), 512, 0, stream>>>(
        xb, k0T, Ab, uS0, b0, h1, H1, D);
    // layer 1
    lora_down<<<(M * 8) / 256, 256, 0, stream>>>(h1, dS1, Ab, H1);
    gemm_lora8<1, u16><<<(M / 256) * (H2 / 256), 512, 0, stream>>>(
        h1, k1T, Ab, uS1, b1, h2, H2, H1);
    // layer 2 (no relu, fp32 out)
    lora_down<<<(M * 8) / 256, 256, 0, stream>>>(h2, dS2, Ab, H2);
    gemm_lora8<0, float><<<(M / 256) * (H3 / 256), 512, 0, stream>>>(
        h2, k2T, Ab, uS2, b2, (float*)d_out, H3, H2);
}

// Round 3
// 293.010 us; speedup vs baseline: 1.1741x; 1.1149x over previous
//
#include <hip/hip_runtime.h>

typedef unsigned short u16;
typedef __attribute__((ext_vector_type(8))) __bf16 bf16x8;
typedef __attribute__((ext_vector_type(8))) unsigned short u16x8;
typedef __attribute__((ext_vector_type(4))) float f32x4;

__device__ __forceinline__ float bf2f(u16 h) {
    return __uint_as_float(((unsigned int)h) << 16);
}
__device__ __forceinline__ u16 f2bf(float f) {
    unsigned int u = __float_as_uint(f);
    u += 0x7fffu + ((u >> 16) & 1u);   // round-to-nearest-even
    return (u16)(u >> 16);
}
__device__ __forceinline__ bf16x8 zero_bf16x8() {
    union { unsigned int u[4]; bf16x8 v; } z;
    z.u[0] = z.u[1] = z.u[2] = z.u[3] = 0u;
    return z.v;
}
__device__ __forceinline__ void gload_lds16(const void* g, void* l) {
    __builtin_amdgcn_global_load_lds(
        (const __attribute__((address_space(1))) unsigned int*)g,
        (__attribute__((address_space(3))) unsigned int*)l, 16, 0, 0);
}
__device__ __forceinline__ void store_out(u16* p, float v)  { *p = f2bf(v); }
__device__ __forceinline__ void store_out(float* p, float v){ *p = v; }

// ================= fused pre-pass (1 launch instead of 10) =================
// block ranges:
//   [0,4096)        cvt x -> xb            (2048 elems/block)
//   [4096,6144)     k0 [1024][2048] -> k0T [2048][1024]   (64 x 32 tiles)
//   [6144,10240)    k1 [2048][2048] -> k1T                (64 x 64)
//   [10240,12288)   k2 [2048][1024] -> k2T [1024][2048]   (32 x 64)
//   [12288,12544)   d0 -> dS0   [12544,13056) d1 -> dS1   [13056,13568) d2 -> dS2
//   [13568,14080)   u0 -> uS0   [14080,14592) u1 -> uS1   [14592,14848) u2 -> uS2

__device__ __forceinline__ void do_cvt(
    const float* __restrict__ in, u16* __restrict__ out, int blk)
{
    int i = (blk * 256 + (int)threadIdx.x) * 8;
    float4 a = *(const float4*)(in + i);
    float4 b = *(const float4*)(in + i + 4);
    u16x8 o;
    o[0] = f2bf(a.x); o[1] = f2bf(a.y); o[2] = f2bf(a.z); o[3] = f2bf(a.w);
    o[4] = f2bf(b.x); o[5] = f2bf(b.y); o[6] = f2bf(b.z); o[7] = f2bf(b.w);
    *(u16x8*)(out + i) = o;
}

__device__ __forceinline__ void do_transpose(
    const float* __restrict__ in, u16* __restrict__ out, int K, int F, int t)
{
    __shared__ u16 tt[32][33];
    int fb = t % (F >> 5), kb = t / (F >> 5);
    int f0 = fb << 5, k0 = kb << 5;
    int lx = threadIdx.x & 31;
    int ly = threadIdx.x >> 5;
#pragma unroll
    for (int i = 0; i < 4; ++i) {
        int k = ly + i * 8;
        tt[k][lx] = f2bf(in[(size_t)(k0 + k) * F + f0 + lx]);
    }
    __syncthreads();
#pragma unroll
    for (int i = 0; i < 4; ++i) {
        int fy = ly + i * 8;
        out[(size_t)(f0 + fy) * K + k0 + lx] = tt[lx][fy];
    }
}

// d: [K][8][8] f32 (d[k][r][t]) -> dS: [T][K][8] bf16 (dS[t][k][r])
__device__ __forceinline__ void do_prep_d(
    const float* __restrict__ d, u16* __restrict__ o, int K, int blk)
{
    int i = blk * 256 + (int)threadIdx.x;
    int r = i & 7;
    int k = (i >> 3) % K;
    int t = i / (K * 8);
    o[i] = f2bf(d[((size_t)k * 8 + r) * 8 + t]);
}

// u: [8][F][8] f32 (u[r][f][t]) -> uS: [T][F][8] bf16, scaled by 2
__device__ __forceinline__ void do_prep_u(
    const float* __restrict__ u, u16* __restrict__ o, int F, int blk)
{
    int i = blk * 256 + (int)threadIdx.x;
    int r = i & 7;
    int f = (i >> 3) % F;
    int t = i / (F * 8);
    o[i] = f2bf(u[((size_t)r * F + f) * 8 + t] * 2.0f);
}

__global__ __launch_bounds__(256) void prep_all(
    const float* x, const float* k0, const float* k1, const float* k2,
    const float* d0, const float* d1, const float* d2,
    const float* u0, const float* u1, const float* u2,
    u16* xb, u16* k0T, u16* k1T, u16* k2T,
    u16* dS0, u16* dS1, u16* dS2, u16* uS0, u16* uS1, u16* uS2)
{
    int b = blockIdx.x;
    if      (b < 4096)  do_cvt(x, xb, b);
    else if (b < 6144)  do_transpose(k0, k0T, 1024, 2048, b - 4096);
    else if (b < 10240) do_transpose(k1, k1T, 2048, 2048, b - 6144);
    else if (b < 12288) do_transpose(k2, k2T, 2048, 1024, b - 10240);
    else if (b < 12544) do_prep_d(d0, dS0, 1024, b - 12288);
    else if (b < 13056) do_prep_d(d1, dS1, 2048, b - 12544);
    else if (b < 13568) do_prep_d(d2, dS2, 2048, b - 13056);
    else if (b < 14080) do_prep_u(u0, uS0, 2048, b - 13568);
    else if (b < 14592) do_prep_u(u1, uS1, 2048, b - 14080);
    else                do_prep_u(u2, uS2, 1024, b - 14592);
}

// ---------------- LoRA down-projection (unchanged) ----------------
__global__ __launch_bounds__(256) void lora_down(
    const u16* __restrict__ H, const u16* __restrict__ dS,
    u16* __restrict__ Aout, int K)
{
    int gt   = blockIdx.x * 256 + threadIdx.x;
    int row  = gt >> 3;
    int oct  = gt & 7;
    int task = row >> 10;
    const u16* hrow = H  + (size_t)row * K;
    const u16* dt   = dS + (size_t)task * K * 8;
    float acc[8];
#pragma unroll
    for (int r = 0; r < 8; ++r) acc[r] = 0.f;
    int kpt  = K >> 3;
    int kbeg = oct * kpt;
    for (int kk = kbeg; kk < kbeg + kpt; kk += 8) {
        u16x8 h8 = *(const u16x8*)(hrow + kk);
#pragma unroll
        for (int j = 0; j < 8; ++j) {
            float hv = bf2f(h8[j]);
            u16x8 dv = *(const u16x8*)(dt + (size_t)(kk + j) * 8);
#pragma unroll
            for (int r = 0; r < 8; ++r)
                acc[r] += hv * bf2f(dv[r]);
        }
    }
#pragma unroll
    for (int r = 0; r < 8; ++r) {
        acc[r] += __shfl_xor(acc[r], 1);
        acc[r] += __shfl_xor(acc[r], 2);
        acc[r] += __shfl_xor(acc[r], 4);
    }
    if (oct == 0) {
        u16x8 o;
#pragma unroll
        for (int r = 0; r < 8; ++r) o[r] = f2bf(acc[r]);
        *(u16x8*)(Aout + (size_t)row * 8) = o;
    }
}

// ============ 256x256 8-phase GEMM + rank-8 LoRA epilogue ==================
// Conflict-free LDS swizzle (first-principles, replaces R2's st_16x32 port):
//   tile half = 128 rows x 64 cols bf16 = 128 rows x 8 chunks of 16B.
//   logical chunk kc of row r lives at physical slot (kc ^ (r&7)).
//   ds_read_b128 instr (fixed mm,ks): lanes (l15,lg) read row base+l15,
//   kc = ks*4+lg -> slot = (ks*4+lg)^(l15&7). For each slot s: lg is
//   determined by l15&3, l15 bit2 fixed, bit3 free -> exactly 8 lanes/slot
//   -> 8 bank-cycles = minimum -> conflict-free.
// Staging (gload_lds writes linearly at tid*16): dest (row,slot) with
//   row = h*128+s*64+(tid>>3), slot = tid&7 holds logical kc = slot^(row&7)
//   -> global src offset = (prow+row)*K*2 + kt*128 + kc*16.
// Schedule: 8 phases/iter, 2 K-tiles/iter, counted vmcnt(4) at P3/P7 only.

#define WAIT_VM4  asm volatile("s_waitcnt vmcnt(4)" ::: "memory")
#define WAIT_VM0  asm volatile("s_waitcnt vmcnt(0)" ::: "memory")
#define WAIT_LGKM0 do { asm volatile("s_waitcnt lgkmcnt(0)" ::: "memory"); \
                        __builtin_amdgcn_sched_barrier(0); } while (0)
#define BARRIER   asm volatile("s_barrier" ::: "memory")
#define PRIO1     __builtin_amdgcn_s_setprio(1)
#define PRIO0     __builtin_amdgcn_s_setprio(0)

#define DS_A(c, mh) do { \
    _Pragma("unroll") for (int mm = 0; mm < 4; ++mm) \
    _Pragma("unroll") for (int ks = 0; ks < 2; ++ks) \
        aF[mm][ks] = *(const bf16x8*)((const char*)&sA[c][0] + \
                       arowb + ((mh)*4+mm)*4096 + (ks ? cb1 : cb0)); } while (0)

#define DS_B(c, nh, bset) do { \
    _Pragma("unroll") for (int nn = 0; nn < 2; ++nn) \
    _Pragma("unroll") for (int ks = 0; ks < 2; ++ks) \
        bset[nn][ks] = *(const bf16x8*)((const char*)&sB[c][0] + \
                       browb + ((nh)*2+nn)*8192 + (ks ? cb1 : cb0)); } while (0)

#define MFMAQ(mh, nh, bset) do { \
    _Pragma("unroll") for (int mm = 0; mm < 4; ++mm) \
    _Pragma("unroll") for (int nn = 0; nn < 2; ++nn) \
    _Pragma("unroll") for (int ks = 0; ks < 2; ++ks) \
        acc[(mh)*4+mm][(nh)*2+nn] = __builtin_amdgcn_mfma_f32_16x16x32_bf16( \
            aF[mm][ks], bset[nn][ks], acc[(mh)*4+mm][(nh)*2+nn], 0, 0, 0); } while (0)

#define STAGE_A(c, h, kt) do { \
    _Pragma("unroll") for (int s = 0; s < 2; ++s) { \
        int P_ = (h)*16384 + s*8192 + tid*16; \
        gload_lds16((const char*)A + (size_t)(unsigned)(aoff[(h)*2+s] + (kt)*128), \
                    (char*)&sA[c][0] + P_); } } while (0)

#define STAGE_B(c, h, kt) do { \
    _Pragma("unroll") for (int s = 0; s < 2; ++s) { \
        int P_ = (h)*16384 + s*8192 + tid*16; \
        gload_lds16((const char*)BT + (size_t)(unsigned)(boff[(h)*2+s] + (kt)*128), \
                    (char*)&sB[c][0] + P_); } } while (0)

template<int RELU, typename OUT_T>
__global__ __launch_bounds__(512, 2) void gemm_lora8(
    const u16* __restrict__ A, const u16* __restrict__ BT,
    const u16* __restrict__ ALR, const u16* __restrict__ US,
    const float* __restrict__ bias, OUT_T* __restrict__ C,
    int N, int K)
{
    __shared__ __align__(16) u16 sA[2][256 * 64];
    __shared__ __align__(16) u16 sB[2][256 * 64];

    const int tid  = threadIdx.x;
    const int lane = tid & 63;
    const int wave = tid >> 6;
    const int wr   = wave >> 2;   // 0..1
    const int wc   = wave & 3;    // 0..3
    const int l15  = lane & 15;
    const int lg   = lane >> 4;

    // bijective XCD swizzle (m204)
    const int nwg = gridDim.x;
    const int orig = blockIdx.x;
    const int q = nwg >> 3, r = nwg & 7;
    const int x = orig & 7, o = orig >> 3;
    const int wg = (x < r ? x * (q + 1) : r * (q + 1) + (x - r) * q) + o;
    const int nbn  = N >> 8;
    const int bm   = wg / nbn;
    const int bn   = wg % nbn;
    const int brow = bm << 8;
    const int bcol = bn << 8;
    const int task = brow >> 10;

    // staging source offsets (bytes, excl. kt term): slot tid&7 holds kc
    int aoff[4], boff[4];
#pragma unroll
    for (int h = 0; h < 2; ++h)
#pragma unroll
        for (int s = 0; s < 2; ++s) {
            int row = h * 128 + s * 64 + (tid >> 3);
            int kc  = (tid & 7) ^ (row & 7);
            aoff[h * 2 + s] = (brow + row) * K * 2 + kc * 16;
            boff[h * 2 + s] = (bcol + row) * K * 2 + kc * 16;
        }

    // ds_read column bases: slot = (ks*4+lg) ^ (l15&7)
    const int rp    = l15 & 7;
    const int cb0   = ((lg ^ (rp & 3)) << 4) | ((rp & 4) << 4);  // ks=0
    const int cb1   = cb0 ^ 64;                                   // ks=1
    const int arowb = (wr * 16 + l15) * 128;
    const int browb = (wc * 16 + l15) * 128;

    f32x4 acc[8][4];
    const f32x4 zf = {0.f, 0.f, 0.f, 0.f};
#pragma unroll
    for (int m = 0; m < 8; ++m)
#pragma unroll
        for (int n = 0; n < 4; ++n) acc[m][n] = zf;

    bf16x8 aF[4][2], bF0[2][2], bF1[2][2];

    // prologue: buf0 <- tile0 (4 halves), buf1 <- tile1 A0,B0
    STAGE_A(0, 0, 0); STAGE_B(0, 0, 0); STAGE_A(0, 1, 0); STAGE_B(0, 1, 0);
    STAGE_A(1, 0, 1); STAGE_B(1, 0, 1);
    WAIT_VM4;          // tile0 complete; buf1 A0,B0 in flight
    BARRIER;

    const int iters = K >> 7;
    for (int i = 0; i < iters; ++i) {
        const int t1 = 2 * i + 1, t2 = 2 * i + 2, t3 = 2 * i + 3;
        const bool nl = (i + 1 < iters);

        // P0: quad(0,0) buf0 ; stage buf1.A1 <- t1
        DS_A(0, 0); DS_B(0, 0, bF0);
        STAGE_A(1, 1, t1);
        BARRIER; WAIT_LGKM0;
        PRIO1; MFMAQ(0, 0, bF0); PRIO0;
        BARRIER;
        // P1: quad(0,1) buf0 ; stage buf1.B1 <- t1
        DS_B(0, 1, bF1);
        STAGE_B(1, 1, t1);
        BARRIER; WAIT_LGKM0;
        PRIO1; MFMAQ(0, 1, bF1); PRIO0;
        BARRIER;
        // P2: quad(1,0) buf0 ; stage buf0.A0 <- t2
        DS_A(0, 1);
        if (nl) STAGE_A(0, 0, t2);
        BARRIER; WAIT_LGKM0;
        PRIO1; MFMAQ(1, 0, bF0); PRIO0;
        BARRIER;
        // P3: quad(1,1) buf0 ; stage buf0.B0 <- t2 ; counted vmcnt
        if (nl) STAGE_B(0, 0, t2);
        BARRIER; WAIT_LGKM0;
        PRIO1; MFMAQ(1, 1, bF1); PRIO0;
        if (nl) { WAIT_VM4; } else { WAIT_VM0; }
        BARRIER;
        // P4: quad(0,0) buf1 ; stage buf0.A1 <- t2
        DS_A(1, 0); DS_B(1, 0, bF0);
        if (nl) STAGE_A(0, 1, t2);
        BARRIER; WAIT_LGKM0;
        PRIO1; MFMAQ(0, 0, bF0); PRIO0;
        BARRIER;
        // P5: quad(0,1) buf1 ; stage buf0.B1 <- t2
        DS_B(1, 1, bF1);
        if (nl) STAGE_B(0, 1, t2);
        BARRIER; WAIT_LGKM0;
        PRIO1; MFMAQ(0, 1, bF1); PRIO0;
        BARRIER;
        // P6: quad(1,0) buf1 ; stage buf1.A0 <- t3
        DS_A(1, 1);
        if (nl) STAGE_A(1, 0, t3);
        BARRIER; WAIT_LGKM0;
        PRIO1; MFMAQ(1, 0, bF0); PRIO0;
        BARRIER;
        // P7: quad(1,1) buf1 ; stage buf1.B0 <- t3 ; counted vmcnt
        if (nl) STAGE_B(1, 0, t3);
        BARRIER; WAIT_LGKM0;
        PRIO1; MFMAQ(1, 1, bF1); PRIO0;
        if (nl) { WAIT_VM4; } else { WAIT_VM0; }
        BARRIER;
    }

    // rank-8 LoRA delta: one extra MFMA round (k 0..7 valid, lanes lg>0 zero)
    bf16x8 z8 = zero_bf16x8();
    bf16x8 bU[4];
#pragma unroll
    for (int n = 0; n < 4; ++n) {
        int col = bcol + n * 64 + wc * 16 + l15;
        bU[n] = (lg == 0) ? *(const bf16x8*)(US + ((size_t)task * N + col) * 8) : z8;
    }
#pragma unroll
    for (int m = 0; m < 8; ++m) {
        int row = brow + m * 32 + wr * 16 + l15;
        bf16x8 aL = (lg == 0) ? *(const bf16x8*)(ALR + (size_t)row * 8) : z8;
#pragma unroll
        for (int n = 0; n < 4; ++n)
            acc[m][n] = __builtin_amdgcn_mfma_f32_16x16x32_bf16(
                aL, bU[n], acc[m][n], 0, 0, 0);
    }

    // bias (+ReLU) + store; C/D: col = lane&15, row = lg*4 + reg
#pragma unroll
    for (int n = 0; n < 4; ++n) {
        int col  = bcol + n * 64 + wc * 16 + l15;
        float bv = bias[col];
#pragma unroll
        for (int m = 0; m < 8; ++m) {
            int row0 = brow + m * 32 + wr * 16 + lg * 4;
#pragma unroll
            for (int rr = 0; rr < 4; ++rr) {
                float v = acc[m][n][rr] + bv;
                if (RELU) v = fmaxf(v, 0.0f);
                store_out(&C[(size_t)(row0 + rr) * N + col], v);
            }
        }
    }
}

// ---------------- launch ----------------

extern "C" void kernel_launch(void* const* d_in, const int* in_sizes, int n_in,
                              void* d_out, int out_size, void* d_ws, size_t ws_size,
                              hipStream_t stream) {
    const float* x  = (const float*)d_in[0];
    const float* k0 = (const float*)d_in[1];
    const float* b0 = (const float*)d_in[2];
    const float* d0 = (const float*)d_in[3];
    const float* u0 = (const float*)d_in[4];
    const float* k1 = (const float*)d_in[5];
    const float* b1 = (const float*)d_in[6];
    const float* d1 = (const float*)d_in[7];
    const float* u1 = (const float*)d_in[8];
    const float* k2 = (const float*)d_in[9];
    const float* b2 = (const float*)d_in[10];
    const float* d2 = (const float*)d_in[11];
    const float* u2 = (const float*)d_in[12];

    const int T = 8, B = 1024, D = 1024, H1 = 2048, H2 = 2048, H3 = 1024;
    const int M = T * B;

    u16* w = (u16*)d_ws;
    size_t off = 0;
    u16* xb  = w + off; off += (size_t)M * D;
    u16* k0T = w + off; off += (size_t)H1 * D;
    u16* k1T = w + off; off += (size_t)H2 * H1;
    u16* k2T = w + off; off += (size_t)H3 * H2;
    u16* dS0 = w + off; off += (size_t)T * D * 8;
    u16* dS1 = w + off; off += (size_t)T * H1 * 8;
    u16* dS2 = w + off; off += (size_t)T * H2 * 8;
    u16* uS0 = w + off; off += (size_t)T * H1 * 8;
    u16* uS1 = w + off; off += (size_t)T * H2 * 8;
    u16* uS2 = w + off; off += (size_t)T * H3 * 8;
    u16* h1  = w + off; off += (size_t)M * H1;
    u16* h2  = w + off; off += (size_t)M * H2;
    u16* Ab  = w + off; off += (size_t)M * 8;
    (void)ws_size; (void)in_sizes; (void)n_in; (void)out_size;

    // fused pre-pass: 1 launch
    prep_all<<<14848, 256, 0, stream>>>(
        x, k0, k1, k2, d0, d1, d2, u0, u1, u2,
        xb, k0T, k1T, k2T, dS0, dS1, dS2, uS0, uS1, uS2);

    // layer 0
    lora_down<<<(M * 8) / 256, 256, 0, stream>>>(xb, dS0, Ab, D);
    gemm_lora8<1, u16><<<(M / 256) * (H1 / 256), 512, 0, stream>>>(
        xb, k0T, Ab, uS0, b0, h1, H1, D);
    // layer 1
    lora_down<<<(M * 8) / 256, 256, 0, stream>>>(h1, dS1, Ab, H1);
    gemm_lora8<1, u16><<<(M / 256) * (H2 / 256), 512, 0, stream>>>(
        h1, k1T, Ab, uS1, b1, h2, H2, H1);
    // layer 2 (no relu, fp32 out)
    lora_down<<<(M * 8) / 256, 256, 0, stream>>>(h2, dS2, Ab, H2);
    gemm_lora8<0, float><<<(M / 256) * (H3 / 256), 512, 0, stream>>>(
        h2, k2T, Ab, uS2, b2, (float*)d_out, H3, H2);
}